// Round 2
// baseline (1015.880 us; speedup 1.0000x reference)
//
#include <hip/hip_runtime.h>

#define NN 50000
#define NE 800000
#define IND 512
#define HIDD 256
#define LATD 64

// ---------------- CSR build ----------------
__global__ void hist_k(const int* __restrict__ ei, int* __restrict__ cnt) {
    int e = blockIdx.x * 256 + threadIdx.x;
    if (e < NE) atomicAdd(&cnt[ei[NE + e]], 1);
}

__global__ __launch_bounds__(1024) void scan_k(const int* __restrict__ cnt,
                                               int* __restrict__ row_ptr) {
    __shared__ int buf[1024];
    int tid = threadIdx.x;
    int carry = 0;
    for (int base = 0; base < NN; base += 1024) {
        int idx = base + tid;
        int v = (idx < NN) ? cnt[idx] : 0;
        buf[tid] = v;
        __syncthreads();
        for (int off = 1; off < 1024; off <<= 1) {
            int t = (tid >= off) ? buf[tid - off] : 0;
            __syncthreads();
            buf[tid] += t;
            __syncthreads();
        }
        if (idx < NN) row_ptr[idx] = carry + buf[tid] - v;  // exclusive
        carry += buf[1023];
        __syncthreads();
    }
    if (tid == 0) row_ptr[NN] = carry;
}

__global__ void scatter_k(const int* __restrict__ ei, const int* __restrict__ row_ptr,
                          int* __restrict__ cursor, int* __restrict__ sorted_src) {
    int e = blockIdx.x * 256 + threadIdx.x;
    if (e >= NE) return;
    int s = ei[e], d = ei[NE + e];
    int pos = row_ptr[d] + atomicAdd(&cursor[d], 1);
    sorted_src[pos] = s;
}

// ---------------- tiled GEMM: C[M,N] = A[M,K] * B[K,N], all f32 ----------------
// TRANSB: B[k][n] = Bptr[n*ldb + k].
// EPI: 0 -> write C only ; 1 -> write C and O ; 2 -> write O only
template <bool TRANSB, int EPI>
__global__ __launch_bounds__(256) void gemm_k(const float* __restrict__ A,
                                              const float* __restrict__ B,
                                              float* __restrict__ C,
                                              float* __restrict__ O,
                                              int M, int N, int K, int ldb) {
    __shared__ float As[16][64];
    __shared__ float Bs[16][64];
    const int tid = threadIdx.x;
    const int tx = tid & 15, ty = tid >> 4;
    const int n0 = blockIdx.x * 64;
    const int m0 = blockIdx.y * 64;

    const int arow = tid >> 2;        // 0..63
    const int ak = (tid & 3) * 4;     // 0,4,8,12
    const int bcol = tid & 63;        // 0..63
    const int bk = (tid >> 6) * 4;    // 0,4,8,12

    float acc[4][4] = {};

    for (int k0 = 0; k0 < K; k0 += 16) {
        int gm = m0 + arow;
        if (gm < M) {
            float4 v = *(const float4*)(A + (size_t)gm * K + k0 + ak);
            As[ak + 0][arow] = v.x;
            As[ak + 1][arow] = v.y;
            As[ak + 2][arow] = v.z;
            As[ak + 3][arow] = v.w;
        } else {
            As[ak + 0][arow] = 0.f;
            As[ak + 1][arow] = 0.f;
            As[ak + 2][arow] = 0.f;
            As[ak + 3][arow] = 0.f;
        }
        if (!TRANSB) {
#pragma unroll
            for (int i = 0; i < 4; i++)
                Bs[bk + i][bcol] = B[(size_t)(k0 + bk + i) * ldb + n0 + bcol];
        } else {
            float4 v = *(const float4*)(B + (size_t)(n0 + bcol) * ldb + k0 + bk);
            Bs[bk + 0][bcol] = v.x;
            Bs[bk + 1][bcol] = v.y;
            Bs[bk + 2][bcol] = v.z;
            Bs[bk + 3][bcol] = v.w;
        }
        __syncthreads();
#pragma unroll
        for (int k = 0; k < 16; k++) {
            float4 a = *(const float4*)&As[k][ty * 4];
            float4 b = *(const float4*)&Bs[k][tx * 4];
            float av[4] = {a.x, a.y, a.z, a.w};
            float bv[4] = {b.x, b.y, b.z, b.w};
#pragma unroll
            for (int i = 0; i < 4; i++)
#pragma unroll
                for (int j = 0; j < 4; j++) acc[i][j] += av[i] * bv[j];
        }
        __syncthreads();
    }

#pragma unroll
    for (int i = 0; i < 4; i++) {
        int gm = m0 + ty * 4 + i;
        if (gm >= M) continue;
#pragma unroll
        for (int j = 0; j < 4; j++) {
            int gn = n0 + tx * 4 + j;
            float v = acc[i][j];
            if (EPI == 0) {
                C[(size_t)gm * N + gn] = v;
            } else if (EPI == 1) {
                C[(size_t)gm * N + gn] = v;
                O[(size_t)gm * N + gn] = v;
            } else {
                O[(size_t)gm * N + gn] = v;
            }
        }
    }
}

// ---------------- per-row attention dots ----------------
__global__ __launch_bounds__(256) void rowdots_k(const float* __restrict__ h1,
                                                 const float* __restrict__ att_s,
                                                 const float* __restrict__ att_d,
                                                 float* __restrict__ a_src,
                                                 float* __restrict__ a_dst) {
    int wave = threadIdx.x >> 6, lane = threadIdx.x & 63;
    int node = blockIdx.x * 4 + wave;
    if (node >= NN) return;
    int c = lane * 4;
    float4 h = *(const float4*)&h1[(size_t)node * HIDD + c];
    float4 s4 = *(const float4*)&att_s[c];
    float4 d4 = *(const float4*)&att_d[c];
    float ps = h.x * s4.x + h.y * s4.y + h.z * s4.z + h.w * s4.w;
    float pd = h.x * d4.x + h.y * d4.y + h.z * d4.z + h.w * d4.w;
    for (int off = 32; off; off >>= 1) {
        ps += __shfl_down(ps, off, 64);
        pd += __shfl_down(pd, off, 64);
    }
    if (lane == 0) {
        a_src[node] = ps;
        a_dst[node] = pd;
    }
}

// ---------------- fused edge softmax + aggregation (+ELU), stores alpha ----------------
__global__ __launch_bounds__(256) void attend1_k(const int* __restrict__ row_ptr,
                                                 const int* __restrict__ sorted_src,
                                                 const float* __restrict__ a_src,
                                                 const float* __restrict__ a_dst,
                                                 const float* __restrict__ h1,
                                                 float* __restrict__ alpha,
                                                 float* __restrict__ h1o) {
    int wave = threadIdx.x >> 6, lane = threadIdx.x & 63;
    int d = blockIdx.x * 4 + wave;
    if (d >= NN) return;
    int beg = row_ptr[d], end = row_ptr[d + 1];
    int deg = end - beg;
    float ad = a_dst[d];

    // pass 1: max logit
    float lm = -3.0e38f;
    for (int t = lane; t < deg; t += 64) {
        int s = sorted_src[beg + t];
        float e = a_src[s] + ad;
        e = e > 0.f ? e : 0.2f * e;
        lm = fmaxf(lm, e);
    }
    for (int off = 32; off; off >>= 1) lm = fmaxf(lm, __shfl_down(lm, off, 64));
    lm = __shfl(lm, 0, 64);

    // pass 2: sum of exp
    float ls = 0.f;
    for (int t = lane; t < deg; t += 64) {
        int s = sorted_src[beg + t];
        float e = a_src[s] + ad;
        e = e > 0.f ? e : 0.2f * e;
        ls += expf(e - lm);
    }
    for (int off = 32; off; off >>= 1) ls += __shfl_down(ls, off, 64);
    ls = __shfl(ls, 0, 64);
    float inv = (deg > 0) ? 1.f / ls : 0.f;

    // pass 3: aggregate (lane covers 4 channels), store final alpha
    int c = lane * 4;
    float4 acc = make_float4(0.f, 0.f, 0.f, 0.f);
    for (int t = 0; t < deg; t++) {
        int s = sorted_src[beg + t];              // wave-uniform broadcast
        float e = a_src[s] + ad;
        e = e > 0.f ? e : 0.2f * e;
        float al = expf(e - lm) * inv;
        if (lane == 0) alpha[beg + t] = al;
        float4 h = *(const float4*)&h1[(size_t)s * HIDD + c];
        acc.x += al * h.x;
        acc.y += al * h.y;
        acc.z += al * h.z;
        acc.w += al * h.w;
    }
    // ELU
    acc.x = acc.x > 0.f ? acc.x : expm1f(acc.x);
    acc.y = acc.y > 0.f ? acc.y : expm1f(acc.y);
    acc.z = acc.z > 0.f ? acc.z : expm1f(acc.z);
    acc.w = acc.w > 0.f ? acc.w : expm1f(acc.w);
    *(float4*)&h1o[(size_t)d * HIDD + c] = acc;
}

// ---------------- second aggregation with cached alpha (+ReLU) ----------------
__global__ __launch_bounds__(256) void attend2_k(const int* __restrict__ row_ptr,
                                                 const int* __restrict__ sorted_src,
                                                 const float* __restrict__ alpha,
                                                 const float* __restrict__ h3,
                                                 float* __restrict__ h3o) {
    int wave = threadIdx.x >> 6, lane = threadIdx.x & 63;
    int d = blockIdx.x * 4 + wave;
    if (d >= NN) return;
    int beg = row_ptr[d], end = row_ptr[d + 1];
    int deg = end - beg;
    int c = lane * 4;
    float4 acc = make_float4(0.f, 0.f, 0.f, 0.f);
    for (int t = 0; t < deg; t++) {
        float al = alpha[beg + t];
        int s = sorted_src[beg + t];
        float4 h = *(const float4*)&h3[(size_t)s * HIDD + c];
        acc.x += al * h.x;
        acc.y += al * h.y;
        acc.z += al * h.z;
        acc.w += al * h.w;
    }
    acc.x = fmaxf(acc.x, 0.f);
    acc.y = fmaxf(acc.y, 0.f);
    acc.z = fmaxf(acc.z, 0.f);
    acc.w = fmaxf(acc.w, 0.f);
    *(float4*)&h3o[(size_t)d * HIDD + c] = acc;
}

extern "C" void kernel_launch(void* const* d_in, const int* in_sizes, int n_in,
                              void* d_out, int out_size, void* d_ws, size_t ws_size,
                              hipStream_t stream) {
    const float* x = (const float*)d_in[0];
    const int* ei = (const int*)d_in[1];
    const float* W1 = (const float*)d_in[2];
    const float* W2 = (const float*)d_in[3];
    const float* att_s = (const float*)d_in[4];
    const float* att_d = (const float*)d_in[5];
    float* out_lat = (float*)d_out;
    float* out_rec = out_lat + (size_t)NN * LATD;

    char* ws = (char*)d_ws;
    size_t off = 0;
    auto alloc = [&](size_t bytes) -> void* {
        void* p = ws + off;
        off += (bytes + 255) & ~(size_t)255;
        return p;
    };
    float* bufA = (float*)alloc((size_t)NN * HIDD * 4);   // h1, later h3
    float* bufB = (float*)alloc((size_t)NN * HIDD * 4);   // h1o, later h3o
    float* lat = (float*)alloc((size_t)NN * LATD * 4);
    float* a_src = (float*)alloc((size_t)NN * 4);
    float* a_dst = (float*)alloc((size_t)NN * 4);
    float* alpha = (float*)alloc((size_t)NE * 4);
    int* cnt = (int*)alloc((size_t)NN * 4);
    int* cursor = (int*)alloc((size_t)NN * 4);
    int* row_ptr = (int*)alloc((size_t)(NN + 1) * 4);
    int* sorted = (int*)alloc((size_t)NE * 4);

    hipMemsetAsync(cnt, 0, (size_t)NN * 4, stream);
    hipMemsetAsync(cursor, 0, (size_t)NN * 4, stream);

    const int EB = (NE + 255) / 256;          // 3125
    const int NB4 = (NN + 3) / 4;             // 12500
    const int MB = (NN + 63) / 64;            // 782

    hist_k<<<EB, 256, 0, stream>>>(ei, cnt);
    scan_k<<<1, 1024, 0, stream>>>(cnt, row_ptr);
    scatter_k<<<EB, 256, 0, stream>>>(ei, row_ptr, cursor, sorted);

    // GEMM1: h1 = x @ W1  [50000,512]x[512,256]
    gemm_k<false, 0><<<dim3(HIDD / 64, MB), 256, 0, stream>>>(
        x, W1, bufA, nullptr, NN, HIDD, IND, HIDD);

    rowdots_k<<<NB4, 256, 0, stream>>>(bufA, att_s, att_d, a_src, a_dst);

    attend1_k<<<NB4, 256, 0, stream>>>(row_ptr, sorted, a_src, a_dst, bufA, alpha, bufB);

    // GEMM2: latent = h1o @ W2 [50000,256]x[256,64]; C -> lat (ws), O -> out_lat
    gemm_k<false, 1><<<dim3(LATD / 64, MB), 256, 0, stream>>>(
        bufB, W2, lat, out_lat, NN, LATD, HIDD, LATD);

    // GEMM3: h3 = latent @ W2^T [50000,64]x[64,256]
    gemm_k<true, 0><<<dim3(HIDD / 64, MB), 256, 0, stream>>>(
        lat, W2, bufA, nullptr, NN, HIDD, LATD, LATD);

    attend2_k<<<NB4, 256, 0, stream>>>(row_ptr, sorted, alpha, bufA, bufB);

    // GEMM4: recon = h3o @ W1^T [50000,256]x[256,512] -> out_rec
    gemm_k<true, 2><<<dim3(IND / 64, MB), 256, 0, stream>>>(
        bufB, W1, nullptr, out_rec, NN, IND, HIDD, HIDD);
}

// Round 3
// 739.432 us; speedup vs baseline: 1.3739x; 1.3739x over previous
//
#include <hip/hip_runtime.h>

#define NN 50000
#define NE 800000
#define IND 512
#define HIDD 256
#define LATD 64

typedef __attribute__((ext_vector_type(8))) short bh8;          // 8 bf16 (MFMA A/B frag)
typedef __attribute__((ext_vector_type(8))) unsigned short us8; // staging loads
typedef __attribute__((ext_vector_type(4))) float f4v;          // MFMA C/D frag

__device__ __forceinline__ unsigned short f2bf(float f) {
    unsigned int x = __float_as_uint(f);
    x += 0x7fffu + ((x >> 16) & 1u);   // RNE
    return (unsigned short)(x >> 16);
}

// ---------------- CSR build ----------------
__global__ void hist_k(const int* __restrict__ ei, int* __restrict__ cnt) {
    int e = blockIdx.x * 256 + threadIdx.x;
    if (e < NE) atomicAdd(&cnt[ei[NE + e]], 1);
}

__global__ __launch_bounds__(1024) void scan_k(const int* __restrict__ cnt,
                                               int* __restrict__ row_ptr) {
    __shared__ int buf[1024];
    int tid = threadIdx.x;
    int carry = 0;
    for (int base = 0; base < NN; base += 1024) {
        int idx = base + tid;
        int v = (idx < NN) ? cnt[idx] : 0;
        buf[tid] = v;
        __syncthreads();
        for (int off = 1; off < 1024; off <<= 1) {
            int t = (tid >= off) ? buf[tid - off] : 0;
            __syncthreads();
            buf[tid] += t;
            __syncthreads();
        }
        if (idx < NN) row_ptr[idx] = carry + buf[tid] - v;  // exclusive
        carry += buf[1023];
        __syncthreads();
    }
    if (tid == 0) row_ptr[NN] = carry;
}

__global__ void scatter_k(const int* __restrict__ ei, const int* __restrict__ row_ptr,
                          int* __restrict__ cursor, int* __restrict__ sorted_src) {
    int e = blockIdx.x * 256 + threadIdx.x;
    if (e >= NE) return;
    int s = ei[e], d = ei[NE + e];
    int pos = row_ptr[d] + atomicAdd(&cursor[d], 1);
    sorted_src[pos] = s;
}

// ---------------- weight prep: W1 f32 -> bf16 (as-is) + transposed bf16 ----------------
__global__ void wprep_k(const float* __restrict__ W1, unsigned short* __restrict__ W1bf,
                        unsigned short* __restrict__ W1T) {
    int i = blockIdx.x * 256 + threadIdx.x;
    if (i >= IND * HIDD) return;
    int k = i / HIDD, n = i % HIDD;
    unsigned short b = f2bf(W1[i]);
    W1bf[i] = b;                 // [IND][HIDD] row-major
    W1T[n * IND + k] = b;        // [HIDD][IND]
}

// ---------------- MFMA GEMM: C[M,BN] = A[M,K] * B[K,BN] ----------------
// BM=64, BK=32. Bt is pre-transposed bf16: Bt[n][k], row stride K (k contiguous).
// AF32: A global is f32 (converted during staging); else A is bf16.
// grid.y = m-tile; grid.x = 1 (BN == full N). blockDim.x == BN (BN/64 waves).
template <int BN, bool AF32>
__global__ __launch_bounds__(BN) void mfma_gemm_k(const void* __restrict__ Araw,
                                                  const unsigned short* __restrict__ Bt,
                                                  float* __restrict__ C,
                                                  int M, int K) {
    constexpr int LDP = 40;                       // padded row stride (ushorts)
    __shared__ unsigned short Asm[64 * LDP];
    __shared__ unsigned short Bsm[BN * LDP];

    const int tid = threadIdx.x;
    const int wave = tid >> 6;
    const int lane = tid & 63;
    const int quad = lane >> 4;
    const int l16 = lane & 15;
    const int m0 = blockIdx.y * 64;

    const float* Af = (const float*)Araw;
    const unsigned short* Abf = (const unsigned short*)Araw;

    f4v acc[4][4];
#pragma unroll
    for (int i = 0; i < 4; i++)
#pragma unroll
        for (int j = 0; j < 4; j++) acc[i][j] = (f4v)(0.f);

    for (int k0 = 0; k0 < K; k0 += 32) {
        // ---- stage A tile (64 x 32) ----
        if (AF32) {
#pragma unroll
            for (int f = tid; f < 512; f += BN) {  // 512 float4-loads of 4
                int row = f >> 3, kc = (f & 7) * 4;
                int gm = m0 + row;
                float4 v = make_float4(0.f, 0.f, 0.f, 0.f);
                if (gm < M) v = *(const float4*)(Af + (size_t)gm * K + k0 + kc);
                ushort4 w;
                w.x = f2bf(v.x); w.y = f2bf(v.y); w.z = f2bf(v.z); w.w = f2bf(v.w);
                *(ushort4*)&Asm[row * LDP + kc] = w;
            }
        } else {
            if (tid < 256) {                       // 256 ushort8-loads of 8
                int row = tid >> 2, kc = (tid & 3) * 8;
                int gm = m0 + row;
                us8 v = {0, 0, 0, 0, 0, 0, 0, 0};
                if (gm < M) v = *(const us8*)(Abf + (size_t)gm * K + k0 + kc);
                *(us8*)&Asm[row * LDP + kc] = v;
            }
        }
        // ---- stage B tile (BN x 32) from Bt[n][k] ----
#pragma unroll
        for (int i = 0; i < 4; i++) {
            int f = i * BN + tid;
            int r = f >> 2, kq = (f & 3) * 8;
            us8 v = *(const us8*)(Bt + (size_t)r * K + k0 + kq);
            *(us8*)&Bsm[r * LDP + kq] = v;
        }
        __syncthreads();

        // ---- fragments + MFMA ----
        bh8 a[4], b[4];
#pragma unroll
        for (int mi = 0; mi < 4; mi++)
            a[mi] = *(const bh8*)&Asm[(mi * 16 + l16) * LDP + quad * 8];
#pragma unroll
        for (int ni = 0; ni < 4; ni++)
            b[ni] = *(const bh8*)&Bsm[(wave * 64 + ni * 16 + l16) * LDP + quad * 8];
#pragma unroll
        for (int mi = 0; mi < 4; mi++)
#pragma unroll
            for (int ni = 0; ni < 4; ni++)
                acc[mi][ni] = __builtin_amdgcn_mfma_f32_16x16x32_bf16(
                    a[mi], b[ni], acc[mi][ni], 0, 0, 0);
        __syncthreads();
    }

    // ---- epilogue: C/D layout col=lane&15, row=quad*4+reg ----
#pragma unroll
    for (int mi = 0; mi < 4; mi++) {
        int rbase = m0 + mi * 16 + quad * 4;
#pragma unroll
        for (int ni = 0; ni < 4; ni++) {
            int gc = wave * 64 + ni * 16 + l16;
#pragma unroll
            for (int r = 0; r < 4; r++) {
                int gr = rbase + r;
                if (gr < M) C[(size_t)gr * BN + gc] = acc[mi][ni][r];
            }
        }
    }
}

// ---------------- tiled SIMT GEMM (f32) for the two small GEMMs ----------------
// TRANSB: B[k][n] = Bptr[n*ldb + k].  EPI: 0 -> C only ; 1 -> C and O
template <bool TRANSB, int EPI>
__global__ __launch_bounds__(256) void gemm_k(const float* __restrict__ A,
                                              const float* __restrict__ B,
                                              float* __restrict__ C,
                                              float* __restrict__ O,
                                              int M, int N, int K, int ldb) {
    __shared__ float As[16][64];
    __shared__ float Bs[16][64];
    const int tid = threadIdx.x;
    const int tx = tid & 15, ty = tid >> 4;
    const int n0 = blockIdx.x * 64;
    const int m0 = blockIdx.y * 64;

    const int arow = tid >> 2;
    const int ak = (tid & 3) * 4;
    const int bcol = tid & 63;
    const int bk = (tid >> 6) * 4;

    float acc[4][4] = {};

    for (int k0 = 0; k0 < K; k0 += 16) {
        int gm = m0 + arow;
        if (gm < M) {
            float4 v = *(const float4*)(A + (size_t)gm * K + k0 + ak);
            As[ak + 0][arow] = v.x;
            As[ak + 1][arow] = v.y;
            As[ak + 2][arow] = v.z;
            As[ak + 3][arow] = v.w;
        } else {
            As[ak + 0][arow] = 0.f;
            As[ak + 1][arow] = 0.f;
            As[ak + 2][arow] = 0.f;
            As[ak + 3][arow] = 0.f;
        }
        if (!TRANSB) {
#pragma unroll
            for (int i = 0; i < 4; i++)
                Bs[bk + i][bcol] = B[(size_t)(k0 + bk + i) * ldb + n0 + bcol];
        } else {
            float4 v = *(const float4*)(B + (size_t)(n0 + bcol) * ldb + k0 + bk);
            Bs[bk + 0][bcol] = v.x;
            Bs[bk + 1][bcol] = v.y;
            Bs[bk + 2][bcol] = v.z;
            Bs[bk + 3][bcol] = v.w;
        }
        __syncthreads();
#pragma unroll
        for (int k = 0; k < 16; k++) {
            float4 a = *(const float4*)&As[k][ty * 4];
            float4 b = *(const float4*)&Bs[k][tx * 4];
            float av[4] = {a.x, a.y, a.z, a.w};
            float bv[4] = {b.x, b.y, b.z, b.w};
#pragma unroll
            for (int i = 0; i < 4; i++)
#pragma unroll
                for (int j = 0; j < 4; j++) acc[i][j] += av[i] * bv[j];
        }
        __syncthreads();
    }

#pragma unroll
    for (int i = 0; i < 4; i++) {
        int gm = m0 + ty * 4 + i;
        if (gm >= M) continue;
#pragma unroll
        for (int j = 0; j < 4; j++) {
            int gn = n0 + tx * 4 + j;
            float v = acc[i][j];
            C[(size_t)gm * N + gn] = v;
            if (EPI == 1) O[(size_t)gm * N + gn] = v;
        }
    }
}

// ---------------- per-row attention dots ----------------
__global__ __launch_bounds__(256) void rowdots_k(const float* __restrict__ h1,
                                                 const float* __restrict__ att_s,
                                                 const float* __restrict__ att_d,
                                                 float* __restrict__ a_src,
                                                 float* __restrict__ a_dst) {
    int wave = threadIdx.x >> 6, lane = threadIdx.x & 63;
    int node = blockIdx.x * 4 + wave;
    if (node >= NN) return;
    int c = lane * 4;
    float4 h = *(const float4*)&h1[(size_t)node * HIDD + c];
    float4 s4 = *(const float4*)&att_s[c];
    float4 d4 = *(const float4*)&att_d[c];
    float ps = h.x * s4.x + h.y * s4.y + h.z * s4.z + h.w * s4.w;
    float pd = h.x * d4.x + h.y * d4.y + h.z * d4.z + h.w * d4.w;
    for (int off = 32; off; off >>= 1) {
        ps += __shfl_down(ps, off, 64);
        pd += __shfl_down(pd, off, 64);
    }
    if (lane == 0) {
        a_src[node] = ps;
        a_dst[node] = pd;
    }
}

// ---------------- fused edge softmax + aggregation (+ELU), stores alpha ----------------
__global__ __launch_bounds__(256) void attend1_k(const int* __restrict__ row_ptr,
                                                 const int* __restrict__ sorted_src,
                                                 const float* __restrict__ a_src,
                                                 const float* __restrict__ a_dst,
                                                 const float* __restrict__ h1,
                                                 float* __restrict__ alpha,
                                                 float* __restrict__ h1o) {
    int wave = threadIdx.x >> 6, lane = threadIdx.x & 63;
    int d = blockIdx.x * 4 + wave;
    if (d >= NN) return;
    int beg = row_ptr[d], end = row_ptr[d + 1];
    int deg = end - beg;
    float ad = a_dst[d];

    float lm = -3.0e38f;
    for (int t = lane; t < deg; t += 64) {
        int s = sorted_src[beg + t];
        float e = a_src[s] + ad;
        e = e > 0.f ? e : 0.2f * e;
        lm = fmaxf(lm, e);
    }
    for (int off = 32; off; off >>= 1) lm = fmaxf(lm, __shfl_down(lm, off, 64));
    lm = __shfl(lm, 0, 64);

    float ls = 0.f;
    for (int t = lane; t < deg; t += 64) {
        int s = sorted_src[beg + t];
        float e = a_src[s] + ad;
        e = e > 0.f ? e : 0.2f * e;
        ls += expf(e - lm);
    }
    for (int off = 32; off; off >>= 1) ls += __shfl_down(ls, off, 64);
    ls = __shfl(ls, 0, 64);
    float inv = (deg > 0) ? 1.f / ls : 0.f;

    int c = lane * 4;
    float4 acc = make_float4(0.f, 0.f, 0.f, 0.f);
    for (int t = 0; t < deg; t++) {
        int s = sorted_src[beg + t];
        float e = a_src[s] + ad;
        e = e > 0.f ? e : 0.2f * e;
        float al = expf(e - lm) * inv;
        if (lane == 0) alpha[beg + t] = al;
        float4 h = *(const float4*)&h1[(size_t)s * HIDD + c];
        acc.x += al * h.x;
        acc.y += al * h.y;
        acc.z += al * h.z;
        acc.w += al * h.w;
    }
    acc.x = acc.x > 0.f ? acc.x : expm1f(acc.x);
    acc.y = acc.y > 0.f ? acc.y : expm1f(acc.y);
    acc.z = acc.z > 0.f ? acc.z : expm1f(acc.z);
    acc.w = acc.w > 0.f ? acc.w : expm1f(acc.w);
    *(float4*)&h1o[(size_t)d * HIDD + c] = acc;
}

// ---------------- second aggregation with cached alpha (+ReLU) -> bf16 ----------------
__global__ __launch_bounds__(256) void attend2_k(const int* __restrict__ row_ptr,
                                                 const int* __restrict__ sorted_src,
                                                 const float* __restrict__ alpha,
                                                 const float* __restrict__ h3,
                                                 unsigned short* __restrict__ h3bf) {
    int wave = threadIdx.x >> 6, lane = threadIdx.x & 63;
    int d = blockIdx.x * 4 + wave;
    if (d >= NN) return;
    int beg = row_ptr[d], end = row_ptr[d + 1];
    int deg = end - beg;
    int c = lane * 4;
    float4 acc = make_float4(0.f, 0.f, 0.f, 0.f);
    for (int t = 0; t < deg; t++) {
        float al = alpha[beg + t];
        int s = sorted_src[beg + t];
        float4 h = *(const float4*)&h3[(size_t)s * HIDD + c];
        acc.x += al * h.x;
        acc.y += al * h.y;
        acc.z += al * h.z;
        acc.w += al * h.w;
    }
    ushort4 o;
    o.x = f2bf(fmaxf(acc.x, 0.f));
    o.y = f2bf(fmaxf(acc.y, 0.f));
    o.z = f2bf(fmaxf(acc.z, 0.f));
    o.w = f2bf(fmaxf(acc.w, 0.f));
    *(ushort4*)&h3bf[(size_t)d * HIDD + c] = o;
}

extern "C" void kernel_launch(void* const* d_in, const int* in_sizes, int n_in,
                              void* d_out, int out_size, void* d_ws, size_t ws_size,
                              hipStream_t stream) {
    const float* x = (const float*)d_in[0];
    const int* ei = (const int*)d_in[1];
    const float* W1 = (const float*)d_in[2];
    const float* W2 = (const float*)d_in[3];
    const float* att_s = (const float*)d_in[4];
    const float* att_d = (const float*)d_in[5];
    float* out_lat = (float*)d_out;
    float* out_rec = out_lat + (size_t)NN * LATD;

    char* ws = (char*)d_ws;
    size_t off = 0;
    auto alloc = [&](size_t bytes) -> void* {
        void* p = ws + off;
        off += (bytes + 255) & ~(size_t)255;
        return p;
    };
    float* bufA = (float*)alloc((size_t)NN * HIDD * 4);   // h1, later h3 (f32)
    float* bufB = (float*)alloc((size_t)NN * HIDD * 4);   // h1o (f32); later h3o (bf16, aliased)
    float* lat = (float*)alloc((size_t)NN * LATD * 4);
    float* a_src = (float*)alloc((size_t)NN * 4);
    float* a_dst = (float*)alloc((size_t)NN * 4);
    float* alpha = (float*)alloc((size_t)NE * 4);
    int* cnt = (int*)alloc((size_t)NN * 4);
    int* cursor = (int*)alloc((size_t)NN * 4);
    int* row_ptr = (int*)alloc((size_t)(NN + 1) * 4);
    int* sorted = (int*)alloc((size_t)NE * 4);
    unsigned short* W1bf = (unsigned short*)alloc((size_t)IND * HIDD * 2);
    unsigned short* W1T = (unsigned short*)alloc((size_t)IND * HIDD * 2);
    unsigned short* h3bf = (unsigned short*)bufB;         // alias: bufB free after GEMM2

    hipMemsetAsync(cnt, 0, (size_t)NN * 4, stream);
    hipMemsetAsync(cursor, 0, (size_t)NN * 4, stream);

    const int EB = (NE + 255) / 256;
    const int NB4 = (NN + 3) / 4;
    const int MB = (NN + 63) / 64;   // 782

    wprep_k<<<(IND * HIDD + 255) / 256, 256, 0, stream>>>(W1, W1bf, W1T);
    hist_k<<<EB, 256, 0, stream>>>(ei, cnt);
    scan_k<<<1, 1024, 0, stream>>>(cnt, row_ptr);
    scatter_k<<<EB, 256, 0, stream>>>(ei, row_ptr, cursor, sorted);

    // GEMM1 (MFMA): h1 = x(f32->bf16) @ W1  [50000,512]x[512,256] -> f32 bufA
    mfma_gemm_k<HIDD, true><<<dim3(1, MB), HIDD, 0, stream>>>(
        (const void*)x, W1T, bufA, NN, IND);

    rowdots_k<<<NB4, 256, 0, stream>>>(bufA, att_s, att_d, a_src, a_dst);
    attend1_k<<<NB4, 256, 0, stream>>>(row_ptr, sorted, a_src, a_dst, bufA, alpha, bufB);

    // GEMM2 (SIMT f32): latent = h1o @ W2 ; C -> lat, O -> out_lat
    gemm_k<false, 1><<<dim3(LATD / 64, MB), 256, 0, stream>>>(
        bufB, W2, lat, out_lat, NN, LATD, HIDD, LATD);

    // GEMM3 (SIMT f32): h3 = latent @ W2^T -> bufA
    gemm_k<true, 0><<<dim3(HIDD / 64, MB), 256, 0, stream>>>(
        lat, W2, bufA, nullptr, NN, HIDD, LATD, LATD);

    attend2_k<<<NB4, 256, 0, stream>>>(row_ptr, sorted, alpha, bufA, h3bf);

    // GEMM4 (MFMA): recon = h3o(bf16) @ W1^T  [50000,256]x[256,512] -> f32 out_rec
    mfma_gemm_k<IND, false><<<dim3(1, MB), IND, 0, stream>>>(
        (const void*)h3bf, W1bf, out_rec, NN, HIDD);
}

// Round 4
// 627.756 us; speedup vs baseline: 1.6183x; 1.1779x over previous
//
#include <hip/hip_runtime.h>

#define NN 50000
#define NE 800000
#define IND 512
#define HIDD 256
#define LATD 64

typedef __attribute__((ext_vector_type(8))) short bh8;          // 8 bf16 (MFMA A/B frag)
typedef __attribute__((ext_vector_type(8))) unsigned short us8; // staging loads
typedef __attribute__((ext_vector_type(4))) float f4v;          // MFMA C/D frag

__device__ __forceinline__ unsigned short f2bf(float f) {
    unsigned int x = __float_as_uint(f);
    x += 0x7fffu + ((x >> 16) & 1u);   // RNE
    return (unsigned short)(x >> 16);
}
__device__ __forceinline__ float bf2f(unsigned short u) {
    return __uint_as_float(((unsigned int)u) << 16);
}

// ---------------- CSR build ----------------
__global__ void hist_k(const int* __restrict__ ei, int* __restrict__ cnt) {
    int e = blockIdx.x * 256 + threadIdx.x;
    if (e < NE) atomicAdd(&cnt[ei[NE + e]], 1);
}

__global__ __launch_bounds__(1024) void scan_k(const int* __restrict__ cnt,
                                               int* __restrict__ row_ptr) {
    __shared__ int buf[1024];
    int tid = threadIdx.x;
    int carry = 0;
    for (int base = 0; base < NN; base += 1024) {
        int idx = base + tid;
        int v = (idx < NN) ? cnt[idx] : 0;
        buf[tid] = v;
        __syncthreads();
        for (int off = 1; off < 1024; off <<= 1) {
            int t = (tid >= off) ? buf[tid - off] : 0;
            __syncthreads();
            buf[tid] += t;
            __syncthreads();
        }
        if (idx < NN) row_ptr[idx] = carry + buf[tid] - v;  // exclusive
        carry += buf[1023];
        __syncthreads();
    }
    if (tid == 0) row_ptr[NN] = carry;
}

__global__ void scatter_k(const int* __restrict__ ei, const int* __restrict__ row_ptr,
                          int* __restrict__ cursor, int* __restrict__ sorted_src) {
    int e = blockIdx.x * 256 + threadIdx.x;
    if (e >= NE) return;
    int s = ei[e], d = ei[NE + e];
    int pos = row_ptr[d] + atomicAdd(&cursor[d], 1);
    sorted_src[pos] = s;
}

// ---------------- weight prep: W1 f32 -> bf16 (as-is) + transposed bf16 ----------------
__global__ void wprep_k(const float* __restrict__ W1, unsigned short* __restrict__ W1bf,
                        unsigned short* __restrict__ W1T) {
    int i = blockIdx.x * 256 + threadIdx.x;
    if (i >= IND * HIDD) return;
    int k = i / HIDD, n = i % HIDD;
    unsigned short b = f2bf(W1[i]);
    W1bf[i] = b;                 // [IND][HIDD] row-major
    W1T[n * IND + k] = b;        // [HIDD][IND]
}

// ---------------- MFMA GEMM: C[M,BN] = A[M,K] * B[K,BN] ----------------
// BM=64, BK=32. Bt pre-transposed bf16: Bt[n][k]. AF32: A f32 (converted in staging).
// CBF16: output written as bf16, else f32.
template <int BN, bool AF32, bool CBF16>
__global__ __launch_bounds__(BN) void mfma_gemm_k(const void* __restrict__ Araw,
                                                  const unsigned short* __restrict__ Bt,
                                                  void* __restrict__ Cout,
                                                  int M, int K) {
    constexpr int LDP = 40;
    __shared__ unsigned short Asm[64 * LDP];
    __shared__ unsigned short Bsm[BN * LDP];

    const int tid = threadIdx.x;
    const int wave = tid >> 6;
    const int lane = tid & 63;
    const int quad = lane >> 4;
    const int l16 = lane & 15;
    const int m0 = blockIdx.y * 64;

    const float* Af = (const float*)Araw;
    const unsigned short* Abf = (const unsigned short*)Araw;

    f4v acc[4][4];
#pragma unroll
    for (int i = 0; i < 4; i++)
#pragma unroll
        for (int j = 0; j < 4; j++) acc[i][j] = (f4v)(0.f);

    for (int k0 = 0; k0 < K; k0 += 32) {
        if (AF32) {
#pragma unroll
            for (int f = tid; f < 512; f += BN) {
                int row = f >> 3, kc = (f & 7) * 4;
                int gm = m0 + row;
                float4 v = make_float4(0.f, 0.f, 0.f, 0.f);
                if (gm < M) v = *(const float4*)(Af + (size_t)gm * K + k0 + kc);
                ushort4 w;
                w.x = f2bf(v.x); w.y = f2bf(v.y); w.z = f2bf(v.z); w.w = f2bf(v.w);
                *(ushort4*)&Asm[row * LDP + kc] = w;
            }
        } else {
            if (tid < 256) {
                int row = tid >> 2, kc = (tid & 3) * 8;
                int gm = m0 + row;
                us8 v = {0, 0, 0, 0, 0, 0, 0, 0};
                if (gm < M) v = *(const us8*)(Abf + (size_t)gm * K + k0 + kc);
                *(us8*)&Asm[row * LDP + kc] = v;
            }
        }
#pragma unroll
        for (int i = 0; i < 4; i++) {
            int f = i * BN + tid;
            int r = f >> 2, kq = (f & 3) * 8;
            us8 v = *(const us8*)(Bt + (size_t)r * K + k0 + kq);
            *(us8*)&Bsm[r * LDP + kq] = v;
        }
        __syncthreads();

        bh8 a[4], b[4];
#pragma unroll
        for (int mi = 0; mi < 4; mi++)
            a[mi] = *(const bh8*)&Asm[(mi * 16 + l16) * LDP + quad * 8];
#pragma unroll
        for (int ni = 0; ni < 4; ni++)
            b[ni] = *(const bh8*)&Bsm[(wave * 64 + ni * 16 + l16) * LDP + quad * 8];
#pragma unroll
        for (int mi = 0; mi < 4; mi++)
#pragma unroll
            for (int ni = 0; ni < 4; ni++)
                acc[mi][ni] = __builtin_amdgcn_mfma_f32_16x16x32_bf16(
                    a[mi], b[ni], acc[mi][ni], 0, 0, 0);
        __syncthreads();
    }

    // epilogue: col=lane&15, row=quad*4+reg
#pragma unroll
    for (int mi = 0; mi < 4; mi++) {
        int rbase = m0 + mi * 16 + quad * 4;
#pragma unroll
        for (int ni = 0; ni < 4; ni++) {
            int gc = wave * 64 + ni * 16 + l16;
#pragma unroll
            for (int r = 0; r < 4; r++) {
                int gr = rbase + r;
                if (gr < M) {
                    if (CBF16)
                        ((unsigned short*)Cout)[(size_t)gr * BN + gc] = f2bf(acc[mi][ni][r]);
                    else
                        ((float*)Cout)[(size_t)gr * BN + gc] = acc[mi][ni][r];
                }
            }
        }
    }
}

// ---------------- tiled SIMT GEMM (f32 in) ----------------
// TRANSB: B[k][n] = Bptr[n*ldb + k].
// EPI: 0 -> f32 C ; 1 -> f32 C + f32 O ; 2 -> bf16 Obf only
template <bool TRANSB, int EPI>
__global__ __launch_bounds__(256) void gemm_k(const float* __restrict__ A,
                                              const float* __restrict__ B,
                                              float* __restrict__ C,
                                              float* __restrict__ O,
                                              unsigned short* __restrict__ Obf,
                                              int M, int N, int K, int ldb) {
    __shared__ float As[16][64];
    __shared__ float Bs[16][64];
    const int tid = threadIdx.x;
    const int tx = tid & 15, ty = tid >> 4;
    const int n0 = blockIdx.x * 64;
    const int m0 = blockIdx.y * 64;

    const int arow = tid >> 2;
    const int ak = (tid & 3) * 4;
    const int bcol = tid & 63;
    const int bk = (tid >> 6) * 4;

    float acc[4][4] = {};

    for (int k0 = 0; k0 < K; k0 += 16) {
        int gm = m0 + arow;
        if (gm < M) {
            float4 v = *(const float4*)(A + (size_t)gm * K + k0 + ak);
            As[ak + 0][arow] = v.x;
            As[ak + 1][arow] = v.y;
            As[ak + 2][arow] = v.z;
            As[ak + 3][arow] = v.w;
        } else {
            As[ak + 0][arow] = 0.f;
            As[ak + 1][arow] = 0.f;
            As[ak + 2][arow] = 0.f;
            As[ak + 3][arow] = 0.f;
        }
        if (!TRANSB) {
#pragma unroll
            for (int i = 0; i < 4; i++)
                Bs[bk + i][bcol] = B[(size_t)(k0 + bk + i) * ldb + n0 + bcol];
        } else {
            float4 v = *(const float4*)(B + (size_t)(n0 + bcol) * ldb + k0 + bk);
            Bs[bk + 0][bcol] = v.x;
            Bs[bk + 1][bcol] = v.y;
            Bs[bk + 2][bcol] = v.z;
            Bs[bk + 3][bcol] = v.w;
        }
        __syncthreads();
#pragma unroll
        for (int k = 0; k < 16; k++) {
            float4 a = *(const float4*)&As[k][ty * 4];
            float4 b = *(const float4*)&Bs[k][tx * 4];
            float av[4] = {a.x, a.y, a.z, a.w};
            float bv[4] = {b.x, b.y, b.z, b.w};
#pragma unroll
            for (int i = 0; i < 4; i++)
#pragma unroll
                for (int j = 0; j < 4; j++) acc[i][j] += av[i] * bv[j];
        }
        __syncthreads();
    }

#pragma unroll
    for (int i = 0; i < 4; i++) {
        int gm = m0 + ty * 4 + i;
        if (gm >= M) continue;
#pragma unroll
        for (int j = 0; j < 4; j++) {
            int gn = n0 + tx * 4 + j;
            float v = acc[i][j];
            if (EPI == 0) {
                C[(size_t)gm * N + gn] = v;
            } else if (EPI == 1) {
                C[(size_t)gm * N + gn] = v;
                O[(size_t)gm * N + gn] = v;
            } else {
                Obf[(size_t)gm * N + gn] = f2bf(v);
            }
        }
    }
}

// ---------------- per-row attention dots (bf16 h1) ----------------
__global__ __launch_bounds__(256) void rowdots_k(const unsigned short* __restrict__ h1bf,
                                                 const float* __restrict__ att_s,
                                                 const float* __restrict__ att_d,
                                                 float* __restrict__ a_src,
                                                 float* __restrict__ a_dst) {
    int wave = threadIdx.x >> 6, lane = threadIdx.x & 63;
    int node = blockIdx.x * 4 + wave;
    if (node >= NN) return;
    int c = lane * 4;
    ushort4 hu = *(const ushort4*)&h1bf[(size_t)node * HIDD + c];
    float4 s4 = *(const float4*)&att_s[c];
    float4 d4 = *(const float4*)&att_d[c];
    float hx = bf2f(hu.x), hy = bf2f(hu.y), hz = bf2f(hu.z), hw = bf2f(hu.w);
    float ps = hx * s4.x + hy * s4.y + hz * s4.z + hw * s4.w;
    float pd = hx * d4.x + hy * d4.y + hz * d4.z + hw * d4.w;
    for (int off = 32; off; off >>= 1) {
        ps += __shfl_down(ps, off, 64);
        pd += __shfl_down(pd, off, 64);
    }
    if (lane == 0) {
        a_src[node] = ps;
        a_dst[node] = pd;
    }
}

__device__ __forceinline__ float lrelu(float e) { return e > 0.f ? e : 0.2f * e; }

// ---------------- fused edge softmax + aggregation (+ELU), stores alpha ----------------
__global__ __launch_bounds__(256) void attend1_k(const int* __restrict__ row_ptr,
                                                 const int* __restrict__ sorted_src,
                                                 const float* __restrict__ a_src,
                                                 const float* __restrict__ a_dst,
                                                 const unsigned short* __restrict__ h1bf,
                                                 float* __restrict__ alpha,
                                                 float* __restrict__ h1o) {
    int wave = threadIdx.x >> 6, lane = threadIdx.x & 63;
    int d = blockIdx.x * 4 + wave;
    if (d >= NN) return;
    int beg = row_ptr[d], end = row_ptr[d + 1];
    int deg = end - beg;
    float ad = a_dst[d];

    // pass 1: max logit (lane-parallel)
    float lm = -3.0e38f;
    for (int t = lane; t < deg; t += 64) {
        int s = sorted_src[beg + t];
        lm = fmaxf(lm, lrelu(a_src[s] + ad));
    }
    for (int off = 32; off; off >>= 1) lm = fmaxf(lm, __shfl_down(lm, off, 64));
    lm = __shfl(lm, 0, 64);

    // pass 2: sum of exp (lane-parallel), cache first-stride ex in register
    float ls = 0.f, ex0 = 0.f;
    for (int t = lane; t < deg; t += 64) {
        int s = sorted_src[beg + t];
        float ex = __expf(lrelu(a_src[s] + ad) - lm);
        if (t == lane) ex0 = ex;
        ls += ex;
    }
    for (int off = 32; off; off >>= 1) ls += __shfl_down(ls, off, 64);
    ls = __shfl(ls, 0, 64);
    float inv = (deg > 0) ? 1.f / ls : 0.f;

    // pass 2.5: store normalized alpha (lane-parallel, one coalesced write)
    if (lane < deg) alpha[beg + lane] = ex0 * inv;
    for (int t = lane + 64; t < deg; t += 64) {
        int s = sorted_src[beg + t];
        alpha[beg + t] = __expf(lrelu(a_src[s] + ad) - lm) * inv;
    }

    // pass 3: aggregate bf16 rows, unroll x4 for ILP
    int c = lane * 4;
    float4 acc = make_float4(0.f, 0.f, 0.f, 0.f);
    int t = 0;
    for (; t + 4 <= deg; t += 4) {
        int s0 = sorted_src[beg + t + 0];
        int s1 = sorted_src[beg + t + 1];
        int s2 = sorted_src[beg + t + 2];
        int s3 = sorted_src[beg + t + 3];
        ushort4 h0 = *(const ushort4*)&h1bf[(size_t)s0 * HIDD + c];
        ushort4 h1v = *(const ushort4*)&h1bf[(size_t)s1 * HIDD + c];
        ushort4 h2 = *(const ushort4*)&h1bf[(size_t)s2 * HIDD + c];
        ushort4 h3 = *(const ushort4*)&h1bf[(size_t)s3 * HIDD + c];
        float a0 = __expf(lrelu(a_src[s0] + ad) - lm) * inv;
        float a1 = __expf(lrelu(a_src[s1] + ad) - lm) * inv;
        float a2 = __expf(lrelu(a_src[s2] + ad) - lm) * inv;
        float a3 = __expf(lrelu(a_src[s3] + ad) - lm) * inv;
        acc.x += a0 * bf2f(h0.x) + a1 * bf2f(h1v.x) + a2 * bf2f(h2.x) + a3 * bf2f(h3.x);
        acc.y += a0 * bf2f(h0.y) + a1 * bf2f(h1v.y) + a2 * bf2f(h2.y) + a3 * bf2f(h3.y);
        acc.z += a0 * bf2f(h0.z) + a1 * bf2f(h1v.z) + a2 * bf2f(h2.z) + a3 * bf2f(h3.z);
        acc.w += a0 * bf2f(h0.w) + a1 * bf2f(h1v.w) + a2 * bf2f(h2.w) + a3 * bf2f(h3.w);
    }
    for (; t < deg; t++) {
        int s = sorted_src[beg + t];
        float al = __expf(lrelu(a_src[s] + ad) - lm) * inv;
        ushort4 h = *(const ushort4*)&h1bf[(size_t)s * HIDD + c];
        acc.x += al * bf2f(h.x);
        acc.y += al * bf2f(h.y);
        acc.z += al * bf2f(h.z);
        acc.w += al * bf2f(h.w);
    }
    acc.x = acc.x > 0.f ? acc.x : expm1f(acc.x);
    acc.y = acc.y > 0.f ? acc.y : expm1f(acc.y);
    acc.z = acc.z > 0.f ? acc.z : expm1f(acc.z);
    acc.w = acc.w > 0.f ? acc.w : expm1f(acc.w);
    *(float4*)&h1o[(size_t)d * HIDD + c] = acc;
}

// ---------------- second aggregation with cached alpha (+ReLU) -> bf16 ----------------
__global__ __launch_bounds__(256) void attend2_k(const int* __restrict__ row_ptr,
                                                 const int* __restrict__ sorted_src,
                                                 const float* __restrict__ alpha,
                                                 const unsigned short* __restrict__ h3bf,
                                                 unsigned short* __restrict__ h3obf) {
    int wave = threadIdx.x >> 6, lane = threadIdx.x & 63;
    int d = blockIdx.x * 4 + wave;
    if (d >= NN) return;
    int beg = row_ptr[d], end = row_ptr[d + 1];
    int deg = end - beg;
    int c = lane * 4;
    float4 acc = make_float4(0.f, 0.f, 0.f, 0.f);
    int t = 0;
    for (; t + 4 <= deg; t += 4) {
        int s0 = sorted_src[beg + t + 0];
        int s1 = sorted_src[beg + t + 1];
        int s2 = sorted_src[beg + t + 2];
        int s3 = sorted_src[beg + t + 3];
        float a0 = alpha[beg + t + 0];
        float a1 = alpha[beg + t + 1];
        float a2 = alpha[beg + t + 2];
        float a3 = alpha[beg + t + 3];
        ushort4 h0 = *(const ushort4*)&h3bf[(size_t)s0 * HIDD + c];
        ushort4 h1v = *(const ushort4*)&h3bf[(size_t)s1 * HIDD + c];
        ushort4 h2 = *(const ushort4*)&h3bf[(size_t)s2 * HIDD + c];
        ushort4 h3 = *(const ushort4*)&h3bf[(size_t)s3 * HIDD + c];
        acc.x += a0 * bf2f(h0.x) + a1 * bf2f(h1v.x) + a2 * bf2f(h2.x) + a3 * bf2f(h3.x);
        acc.y += a0 * bf2f(h0.y) + a1 * bf2f(h1v.y) + a2 * bf2f(h2.y) + a3 * bf2f(h3.y);
        acc.z += a0 * bf2f(h0.z) + a1 * bf2f(h1v.z) + a2 * bf2f(h2.z) + a3 * bf2f(h3.z);
        acc.w += a0 * bf2f(h0.w) + a1 * bf2f(h1v.w) + a2 * bf2f(h2.w) + a3 * bf2f(h3.w);
    }
    for (; t < deg; t++) {
        float al = alpha[beg + t];
        int s = sorted_src[beg + t];
        ushort4 h = *(const ushort4*)&h3bf[(size_t)s * HIDD + c];
        acc.x += al * bf2f(h.x);
        acc.y += al * bf2f(h.y);
        acc.z += al * bf2f(h.z);
        acc.w += al * bf2f(h.w);
    }
    ushort4 o;
    o.x = f2bf(fmaxf(acc.x, 0.f));
    o.y = f2bf(fmaxf(acc.y, 0.f));
    o.z = f2bf(fmaxf(acc.z, 0.f));
    o.w = f2bf(fmaxf(acc.w, 0.f));
    *(ushort4*)&h3obf[(size_t)d * HIDD + c] = o;
}

extern "C" void kernel_launch(void* const* d_in, const int* in_sizes, int n_in,
                              void* d_out, int out_size, void* d_ws, size_t ws_size,
                              hipStream_t stream) {
    const float* x = (const float*)d_in[0];
    const int* ei = (const int*)d_in[1];
    const float* W1 = (const float*)d_in[2];
    const float* W2 = (const float*)d_in[3];
    const float* att_s = (const float*)d_in[4];
    const float* att_d = (const float*)d_in[5];
    float* out_lat = (float*)d_out;
    float* out_rec = out_lat + (size_t)NN * LATD;

    char* ws = (char*)d_ws;
    size_t off = 0;
    auto alloc = [&](size_t bytes) -> void* {
        void* p = ws + off;
        off += (bytes + 255) & ~(size_t)255;
        return p;
    };
    unsigned short* h1bf = (unsigned short*)alloc((size_t)NN * HIDD * 2);  // later h3bf
    float* bufB = (float*)alloc((size_t)NN * HIDD * 4);   // h1o f32; later h3obf (bf16)
    float* lat = (float*)alloc((size_t)NN * LATD * 4);
    float* a_src = (float*)alloc((size_t)NN * 4);
    float* a_dst = (float*)alloc((size_t)NN * 4);
    float* alpha = (float*)alloc((size_t)NE * 4);
    int* cnt = (int*)alloc((size_t)NN * 4);
    int* cursor = (int*)alloc((size_t)NN * 4);
    int* row_ptr = (int*)alloc((size_t)(NN + 1) * 4);
    int* sorted = (int*)alloc((size_t)NE * 4);
    unsigned short* W1bf = (unsigned short*)alloc((size_t)IND * HIDD * 2);
    unsigned short* W1T = (unsigned short*)alloc((size_t)IND * HIDD * 2);
    unsigned short* h3bf = h1bf;                         // alias: h1bf dead after attend1
    unsigned short* h3obf = (unsigned short*)bufB;       // alias: bufB dead after GEMM2

    hipMemsetAsync(cnt, 0, (size_t)NN * 4, stream);
    hipMemsetAsync(cursor, 0, (size_t)NN * 4, stream);

    const int EB = (NE + 255) / 256;
    const int NB4 = (NN + 3) / 4;
    const int MB = (NN + 63) / 64;   // 782

    wprep_k<<<(IND * HIDD + 255) / 256, 256, 0, stream>>>(W1, W1bf, W1T);
    hist_k<<<EB, 256, 0, stream>>>(ei, cnt);
    scan_k<<<1, 1024, 0, stream>>>(cnt, row_ptr);
    scatter_k<<<EB, 256, 0, stream>>>(ei, row_ptr, cursor, sorted);

    // GEMM1 (MFMA): h1 = x(f32->bf16) @ W1 -> bf16 h1bf
    mfma_gemm_k<HIDD, true, true><<<dim3(1, MB), HIDD, 0, stream>>>(
        (const void*)x, W1T, (void*)h1bf, NN, IND);

    rowdots_k<<<NB4, 256, 0, stream>>>(h1bf, att_s, att_d, a_src, a_dst);
    attend1_k<<<NB4, 256, 0, stream>>>(row_ptr, sorted, a_src, a_dst, h1bf, alpha, bufB);

    // GEMM2 (SIMT f32): latent = h1o @ W2 ; C -> lat, O -> out_lat
    gemm_k<false, 1><<<dim3(LATD / 64, MB), 256, 0, stream>>>(
        bufB, W2, lat, out_lat, nullptr, NN, LATD, HIDD, LATD);

    // GEMM3 (SIMT f32): h3 = latent @ W2^T -> bf16 h3bf
    gemm_k<true, 2><<<dim3(HIDD / 64, MB), 256, 0, stream>>>(
        lat, W2, nullptr, nullptr, h3bf, NN, HIDD, LATD, LATD);

    attend2_k<<<NB4, 256, 0, stream>>>(row_ptr, sorted, alpha, h3bf, h3obf);

    // GEMM4 (MFMA): recon = h3o(bf16) @ W1^T -> f32 out_rec
    mfma_gemm_k<IND, false, false><<<dim3(1, MB), IND, 0, stream>>>(
        (const void*)h3obf, W1bf, (void*)out_rec, NN, HIDD);
}